// Round 1
// baseline (651.732 us; speedup 1.0000x reference)
//
#include <hip/hip_runtime.h>

#define HH 640
#define WW 640
#define CIN 3
#define COUT 64
#define KK 7
#define PADV 3
#define NS 100000
#define OHh 319
#define OWw 319

// ---- detect int64-vs-int32 layout of update_location ----
// Scans the first 200000 32-bit words at odd indices. If the input is int64
// (little-endian, values in [0,640)), those are all high-words == 0.
// If int32, they are interleaved row/col values -> OR is nonzero w.p. ~1.
__global__ void detect_kernel(const int* __restrict__ loc, int* __restrict__ flag) {
    __shared__ int red[256];
    int acc = 0;
    for (int i = 1 + (int)threadIdx.x * 2; i < 2 * NS; i += 512) acc |= loc[i];
    red[threadIdx.x] = acc;
    __syncthreads();
    for (int s = 128; s > 0; s >>= 1) {
        if ((int)threadIdx.x < s) red[threadIdx.x] |= red[threadIdx.x + s];
        __syncthreads();
    }
    if (threadIdx.x == 0) flag[0] = red[0];
}

__device__ __forceinline__ void load_loc(const int* loc, bool is64, int n, int& row, int& col) {
    if (is64) { row = loc[4 * n]; col = loc[4 * n + 2]; }
    else      { row = loc[2 * n]; col = loc[2 * n + 1]; }
}

// ---- owner map: last-write-wins via max site index ----
__global__ void owner_kernel(const int* __restrict__ loc, const int* __restrict__ flag,
                             int* __restrict__ owner) {
    int n = blockIdx.x * blockDim.x + threadIdx.x;
    if (n >= NS) return;
    bool is64 = (flag[0] == 0);
    int row, col;
    load_loc(loc, is64, n, row, col);
    atomicMax(&owner[row * WW + col], n);
}

// ---- per-site conv + BN + ReLU -> feats[NS][64] ----
__global__ __launch_bounds__(256) void feats_kernel(
        const int* __restrict__ loc, const float* __restrict__ fm,
        const float* __restrict__ wgt, const float* __restrict__ gamma,
        const float* __restrict__ beta, const float* __restrict__ mean,
        const float* __restrict__ var, const int* __restrict__ flag,
        float* __restrict__ feats) {
    __shared__ float wl[KK * KK * CIN * COUT];  // 9408 floats = 36.75 KB
    for (int i = threadIdx.x; i < KK * KK * CIN * COUT; i += 256) wl[i] = wgt[i];
    __syncthreads();

    const int lane = threadIdx.x & 63;   // channel
    const int wave = threadIdx.x >> 6;   // site within block
    const int n = blockIdx.x * 4 + wave;
    if (n >= NS) return;

    const bool is64 = (flag[0] == 0);
    const float inv = gamma[lane] * rsqrtf(var[lane] + 1e-5f);
    const float bias = beta[lane] - mean[lane] * inv;

    int row, col;
    load_loc(loc, is64, n, row, col);

    float acc = 0.0f;
    int t = 0;
    #pragma unroll
    for (int i = 0; i < KK; ++i) {
        const int r = row + i - PADV;
        const bool rok = ((unsigned)r < HH);
        const float* rowp = fm + (size_t)r * WW * CIN;
        #pragma unroll
        for (int j = 0; j < KK; ++j) {
            const int c = col + j - PADV;
            const bool ok = rok && ((unsigned)c < WW);
            const float* p = rowp + c * CIN;
            #pragma unroll
            for (int ci = 0; ci < CIN; ++ci) {
                const float v = ok ? p[ci] : 0.0f;   // wave-uniform broadcast load
                acc += v * wl[t * COUT + lane];       // coalesced LDS, 2-way (free)
                ++t;
            }
        }
    }
    feats[(size_t)n * COUT + lane] = fmaxf(acc * inv + bias, 0.0f);
}

// ---- 3x3 stride-2 max pool straight from owner map + feats ----
__global__ __launch_bounds__(256) void pool_kernel(
        const int* __restrict__ owner, const float* __restrict__ feats,
        float* __restrict__ out) {
    const int lane = threadIdx.x & 63;
    const int pix = blockIdx.x * 4 + (threadIdx.x >> 6);
    if (pix >= OHh * OWw) return;
    const int oh = pix / OWw, ow = pix % OWw;
    const int r0 = oh * 2, c0 = ow * 2;
    float m = 0.0f;
    #pragma unroll
    for (int dy = 0; dy < 3; ++dy) {
        const int* orow = owner + (r0 + dy) * WW + c0;
        #pragma unroll
        for (int dx = 0; dx < 3; ++dx) {
            const int o = orow[dx];                  // wave-uniform
            if (o >= 0) m = fmaxf(m, feats[(size_t)o * COUT + lane]);
        }
    }
    out[(size_t)pix * COUT + lane] = m;
}

extern "C" void kernel_launch(void* const* d_in, const int* in_sizes, int n_in,
                              void* d_out, int out_size, void* d_ws, size_t ws_size,
                              hipStream_t stream) {
    const int*   loc   = (const int*)d_in[0];
    const float* fm    = (const float*)d_in[1];
    const float* wgt   = (const float*)d_in[2];
    const float* gamma = (const float*)d_in[3];
    const float* beta  = (const float*)d_in[4];
    const float* mean  = (const float*)d_in[5];
    const float* var   = (const float*)d_in[6];
    float* out = (float*)d_out;

    char* ws = (char*)d_ws;
    int* flag   = (int*)ws;                                   // 4 B
    int* owner  = (int*)(ws + 64);                            // 640*640*4 = 1.6 MB
    float* feats = (float*)(ws + 64 + (size_t)HH * WW * 4);   // 100000*64*4 = 25.6 MB

    detect_kernel<<<1, 256, 0, stream>>>(loc, flag);
    hipMemsetAsync(owner, 0xFF, (size_t)HH * WW * sizeof(int), stream);  // owner = -1
    owner_kernel<<<(NS + 255) / 256, 256, 0, stream>>>(loc, flag, owner);
    feats_kernel<<<(NS + 3) / 4, 256, 0, stream>>>(loc, fm, wgt, gamma, beta, mean, var, flag, feats);
    pool_kernel<<<(OHh * OWw + 3) / 4, 256, 0, stream>>>(owner, feats, out);
}